// Round 1
// baseline (337.420 us; speedup 1.0000x reference)
//
#include <hip/hip_runtime.h>

// GuidedAttentionLoss: out = sum_{b,n,t} W[b,n,t] * A[b,n,t] / B
// W = mask ? 1 - exp(-((n/seq_len - t/mel_len)^2) / (2 g^2)) : 0
// A: (B=64, N=512, T=2048) fp32. Memory-bound reduction; skip rows with
// n >= seq_len[b] (zero contribution, no load) and column tail t >= mel_len[b].

#define GAL_B 64
#define GAL_N 512
#define GAL_T 2048

__global__ __launch_bounds__(256) void gal_main(
    const float* __restrict__ A,
    const float* __restrict__ gptr,
    const int*   __restrict__ mel_lens,
    const int*   __restrict__ seq_lens,
    float*       __restrict__ partials)
{
    const int row = blockIdx.x;        // 0 .. B*N-1
    const int b   = row >> 9;          // / 512
    const int n   = row & (GAL_N - 1);
    const int seq = seq_lens[b];

    float local = 0.0f;
    if (n < seq) {
        const int   mel     = mel_lens[b];
        const float g       = gptr[0];
        const float inv2g2  = 1.0f / (2.0f * g * g);
        const float nf      = (float)n / (float)seq;
        const float inv_mel = 1.0f / (float)mel;
        const float4* Arow  = (const float4*)(A + ((size_t)row << 11));
        const int nvec = (mel + 3) >> 2;   // float4's overlapping valid region
        for (int j = threadIdx.x; j < nvec; j += 256) {
            float4 a = Arow[j];
            const int t0 = j << 2;
            {
                float d = nf - (float)(t0 + 0) * inv_mel;
                float w = 1.0f - __expf(-d * d * inv2g2);
                local += (t0 + 0 < mel) ? w * a.x : 0.0f;
            }
            {
                float d = nf - (float)(t0 + 1) * inv_mel;
                float w = 1.0f - __expf(-d * d * inv2g2);
                local += (t0 + 1 < mel) ? w * a.y : 0.0f;
            }
            {
                float d = nf - (float)(t0 + 2) * inv_mel;
                float w = 1.0f - __expf(-d * d * inv2g2);
                local += (t0 + 2 < mel) ? w * a.z : 0.0f;
            }
            {
                float d = nf - (float)(t0 + 3) * inv_mel;
                float w = 1.0f - __expf(-d * d * inv2g2);
                local += (t0 + 3 < mel) ? w * a.w : 0.0f;
            }
        }
    }

    // wave64 reduce
    #pragma unroll
    for (int off = 32; off > 0; off >>= 1)
        local += __shfl_down(local, off, 64);

    __shared__ float s[4];
    const int lane = threadIdx.x & 63;
    const int wave = threadIdx.x >> 6;
    if (lane == 0) s[wave] = local;
    __syncthreads();
    if (threadIdx.x == 0)
        partials[blockIdx.x] = (s[0] + s[1]) + (s[2] + s[3]);
}

__global__ __launch_bounds__(256) void gal_reduce(
    const float* __restrict__ partials, int n, float* __restrict__ out)
{
    // n is a multiple of 1024 here (32768); vectorized read
    const float4* p4 = (const float4*)partials;
    const int nv = n >> 2;
    float local = 0.0f;
    for (int i = threadIdx.x; i < nv; i += 256) {
        float4 v = p4[i];
        local += (v.x + v.y) + (v.z + v.w);
    }
    #pragma unroll
    for (int off = 32; off > 0; off >>= 1)
        local += __shfl_down(local, off, 64);
    __shared__ float s[4];
    if ((threadIdx.x & 63) == 0) s[threadIdx.x >> 6] = local;
    __syncthreads();
    if (threadIdx.x == 0)
        out[0] = ((s[0] + s[1]) + (s[2] + s[3])) * (1.0f / (float)GAL_B);
}

extern "C" void kernel_launch(void* const* d_in, const int* in_sizes, int n_in,
                              void* d_out, int out_size, void* d_ws, size_t ws_size,
                              hipStream_t stream) {
    const float* A        = (const float*)d_in[0];
    const float* g        = (const float*)d_in[1];
    const int*   mel_lens = (const int*)d_in[2];
    const int*   seq_lens = (const int*)d_in[3];
    float* out      = (float*)d_out;
    float* partials = (float*)d_ws;   // 32768 floats = 128 KB

    const int nrows = GAL_B * GAL_N;  // 32768 blocks, one row each
    gal_main<<<nrows, 256, 0, stream>>>(A, g, mel_lens, seq_lens, partials);
    gal_reduce<<<1, 256, 0, stream>>>(partials, nrows, out);
}